// Round 15
// baseline (194.864 us; speedup 1.0000x reference)
//
#include <hip/hip_runtime.h>
#include <hip/hip_bf16.h>

#define W_WORDS 2048
#define H_DIM   1024
#define C_LAB   32
#define HID_D   512
#define MAXW    12
#define NSPAN   (W_WORDS * MAXW)

typedef __attribute__((ext_vector_type(8))) short bf16x8;
typedef __attribute__((ext_vector_type(4))) float f32x4;
typedef __attribute__((ext_vector_type(4))) int i32x4;
typedef __attribute__((ext_vector_type(8))) int i32x8;

__device__ __forceinline__ unsigned short f2b(float x) {
  union { float f; unsigned int i; } v; v.f = x;
  unsigned int r = v.i + 0x7FFFu + ((v.i >> 16) & 1u);
  return (unsigned short)(r >> 16);
}
__device__ __forceinline__ float b2f(unsigned short b) {
  union { float f; unsigned int i; } v; v.i = ((unsigned int)b) << 16;
  return v.f;
}

// f32 -> OCP e4m3fn, RNE, satfinite(448)
__device__ __forceinline__ unsigned char f2e4m3(float x) {
  union { float f; unsigned u; } v; v.f = x;
  unsigned sign = (v.u >> 31) << 7;
  v.u &= 0x7FFFFFFFu;
  if (v.f > 448.f) v.f = 448.f;
  int e8 = (int)(v.u >> 23) - 120;
  unsigned r;
  if (e8 >= 1) {
    unsigned m = v.u & 0x7FFFFFu;
    unsigned keep = m >> 20;
    unsigned rest = m & 0xFFFFFu;
    keep += (rest > 0x80000u) || (rest == 0x80000u && (keep & 1u));
    if (keep == 8u) { keep = 0u; ++e8; }
    if (e8 >= 16) { e8 = 15; keep = 6u; }
    else if (e8 == 15 && keep == 7u) keep = 6u;  // avoid NaN encoding
    r = (unsigned)((e8 << 3) | keep);
  } else {
    int m = (int)(v.f * 512.f + 0.5f);
    r = (m >= 8) ? 0x08u : (unsigned)m;
  }
  return (unsigned char)(r | sign);
}

#define GLOAD_LDS16(g, l)                                                    \
  __builtin_amdgcn_global_load_lds(                                          \
      (const __attribute__((address_space(1))) unsigned int*)(g),            \
      (__attribute__((address_space(3))) unsigned int*)(l), 16, 0, 0)

// ---------- mega0: transposes (z<6) + gather fp8 (z==6) + Wtb0 cvt (z==7) ----------
__global__ void mega0_k(const float* __restrict__ hs, const int* __restrict__ wm,
    unsigned char* __restrict__ we8,
    const float* __restrict__ Wt, const float* __restrict__ W1a,
    const float* __restrict__ Wsp1, const float* __restrict__ W1c,
    const float* __restrict__ Wsp2,
    unsigned char* __restrict__ WtT8, unsigned short* __restrict__ W1aT,
    unsigned char* __restrict__ Wsp1Tc8, float* __restrict__ W1cT,
    float* __restrict__ Wsp2T, unsigned short* __restrict__ Wtb0) {
  if (blockIdx.z == 6) {  // gather: we8[m-1] = fp8(hs[t] * 16)
    int t = blockIdx.y * 96 + blockIdx.x;
    int m = wm[t];
    if (m <= 0) return;
    const float* src = hs + (size_t)t * H_DIM;
    unsigned char* dst = we8 + (size_t)(m - 1) * H_DIM;
    int i = (threadIdx.y * 32 + threadIdx.x) * 4;
    float4 v = *(const float4*)(src + i);
    unsigned u = (unsigned)f2e4m3(v.x * 16.f)
               | ((unsigned)f2e4m3(v.y * 16.f) << 8)
               | ((unsigned)f2e4m3(v.z * 16.f) << 16)
               | ((unsigned)f2e4m3(v.w * 16.f) << 24);
    *(unsigned*)(dst + i) = u;
    return;
  }
  int c0 = blockIdx.x * 32, r0 = blockIdx.y * 32;
  if (blockIdx.z == 7) {  // Wtb0[h][g] = bf16(Wt[h][g]), g<1024
    if (c0 >= 1024) return;
    for (int i = threadIdx.y; i < 32; i += 8)
      Wtb0[(size_t)(r0 + i) * 1024 + c0 + threadIdx.x] =
          f2b(Wt[(size_t)(r0 + i) * 2048 + c0 + threadIdx.x]);
    return;
  }
  const float* in;
  void* out;
  int R, C, ld, mode;  // mode: 0=f32, 1=bf16, 2=fp8 x64
  switch (blockIdx.z) {
    case 0: in = Wt + 1024; out = WtT8; R = 1024; C = 1024; ld = 2048; mode = 2; break;
    case 1: in = W1a;  out = W1aT;   R = 1024; C = 512;  ld = 512;  mode = 1; break;
    case 2: in = Wsp1; out = Wsp1Tc8; R = 1024; C = 1024; ld = 1024; mode = 2; break;
    case 3: in = Wsp1 + 1048576; out = Wsp1Tc8 + 1048576; R = 1024; C = 1024; ld = 1024; mode = 2; break;
    case 4: in = W1c;  out = W1cT;   R = 1024; C = 512;  ld = 512;  mode = 0; break;
    default: in = Wsp2; out = Wsp2T; R = 1024; C = 1024; ld = 1024; mode = 0; break;
  }
  if (c0 >= C || r0 >= R) return;
  __shared__ float tile[32][33];
  for (int i = threadIdx.y; i < 32; i += 8)
    tile[i][threadIdx.x] = in[(size_t)(r0 + i) * ld + c0 + threadIdx.x];
  __syncthreads();
  if (mode == 2) {
    unsigned char* o = (unsigned char*)out;
    for (int i = threadIdx.y; i < 32; i += 8)
      o[(size_t)(c0 + i) * R + r0 + threadIdx.x] = f2e4m3(tile[threadIdx.x][i] * 64.f);
  } else if (mode == 1) {
    unsigned short* o = (unsigned short*)out;
    for (int i = threadIdx.y; i < 32; i += 8)
      o[(size_t)(c0 + i) * R + r0 + threadIdx.x] = f2b(tile[threadIdx.x][i]);
  } else {
    float* o = (float*)out;
    for (int i = threadIdx.y; i < 32; i += 8)
      o[(size_t)(c0 + i) * R + r0 + threadIdx.x] = tile[threadIdx.x][i];
  }
}

// ---------- small GEMM body, 8 A-rows per block ----------
__device__ __forceinline__ void rgemm8_body(int N, int M,
    const float* __restrict__ A, int lda, const float* __restrict__ B, int ldb,
    const float* __restrict__ bias, float* __restrict__ out, int ldc,
    int bx, int by, float* shf) {
  float (*Asm)[1024] = (float(*)[1024])shf;
  float (*red)[16][8] = (float(*)[16][8])(shf + 8192);
  int m0 = by * 8;
  for (int idx = threadIdx.x; idx < 8 * 1024; idx += 256) {
    int mm = idx >> 10, kk = idx & 1023;
    Asm[mm][kk] = (m0 + mm < M) ? A[(size_t)(m0 + mm) * lda + kk] : 0.f;
  }
  __syncthreads();
  int tx = threadIdx.x & 15, ty = threadIdx.x >> 4;
  int n = bx * 16 + tx;
  float acc[8] = {0.f, 0.f, 0.f, 0.f, 0.f, 0.f, 0.f, 0.f};
  if (n < N) {
    for (int k = ty * 64; k < ty * 64 + 64; ++k) {
      float bv = B[(size_t)k * ldb + n];
#pragma unroll
      for (int mm = 0; mm < 8; ++mm) acc[mm] = fmaf(Asm[mm][k], bv, acc[mm]);
    }
  }
#pragma unroll
  for (int mm = 0; mm < 8; ++mm) red[ty][tx][mm] = acc[mm];
  __syncthreads();
  if (ty < 8 && n < N && m0 + ty < M) {
    float s = 0.f;
#pragma unroll
    for (int q = 0; q < 16; ++q) s += red[q][tx][ty];
    if (bias) s += bias[n];
    out[(size_t)(m0 + ty) * ldc + n] = s;
  }
}

// lab = L@Wl+bl (z=0) and MmTf = L@Wsp2T (z=1)
__global__ __launch_bounds__(256) void rgemm8z_k(
    const float* __restrict__ L, const float* __restrict__ Wl,
    const float* __restrict__ bl, float* __restrict__ lab,
    const float* __restrict__ Wsp2T, float* __restrict__ MmTf) {
  __shared__ float shf[10240];
  if (blockIdx.z == 0) {
    rgemm8_body(2048, 32, L, 1024, Wl, 2048, bl, lab, 2048, blockIdx.x, blockIdx.y, shf);
  } else {
    if (blockIdx.x >= 64) return;
    rgemm8_body(1024, 32, L, 1024, Wsp2T, 1024, nullptr, MmTf, 1024,
                blockIdx.x, blockIdx.y, shf);
  }
}

// ---------- mega1: kmat(fp8) + BvecB + misc + bt0A + wfuse MFMA tiles ----------
__global__ __launch_bounds__(256) void mega1_k(
    const float* __restrict__ lab, const float* __restrict__ W1cT,
    unsigned char* __restrict__ KT8,
    const float* __restrict__ W1b, const float* __restrict__ b1,
    float* __restrict__ BvecB,
    const float* __restrict__ bsp2, const float* __restrict__ L,
    float* __restrict__ cv, const float* __restrict__ MmTf,
    unsigned short* __restrict__ MmTb, const float* __restrict__ W2,
    unsigned short* __restrict__ W2padT, const float* __restrict__ bsp1,
    unsigned short* __restrict__ bsp1b,
    const float* __restrict__ bt, const float* __restrict__ W1a,
    float* __restrict__ bt0A,
    const unsigned short* __restrict__ W1aT, const unsigned short* __restrict__ Wtb0,
    unsigned char* __restrict__ WfuseT8) {
  __shared__ __align__(16) unsigned char shraw[65536];
  float* shf = (float*)shraw;
  int g = blockIdx.x;
  if (g < 8192) {  // KT8[(c*512+d)][h] = fp8(l1[c][h] * W1c[h][d] * 1024)
    size_t gid = (size_t)g * 256 + threadIdx.x;
    int row = (int)(gid >> 7);
    int h0 = ((int)gid & 127) * 8;
    int c = row >> 9, d = row & 511;
    const float* lp = lab + (size_t)c * 2048 + 1024 + h0;
    const float* wp = W1cT + (size_t)d * 1024 + h0;
    float4 l0 = *(const float4*)lp, l1 = *(const float4*)(lp + 4);
    float4 w0 = *(const float4*)wp, w1 = *(const float4*)(wp + 4);
    unsigned u0 = (unsigned)f2e4m3(l0.x * w0.x * 1024.f)
                | ((unsigned)f2e4m3(l0.y * w0.y * 1024.f) << 8)
                | ((unsigned)f2e4m3(l0.z * w0.z * 1024.f) << 16)
                | ((unsigned)f2e4m3(l0.w * w0.w * 1024.f) << 24);
    unsigned u1 = (unsigned)f2e4m3(l1.x * w1.x * 1024.f)
                | ((unsigned)f2e4m3(l1.y * w1.y * 1024.f) << 8)
                | ((unsigned)f2e4m3(l1.z * w1.z * 1024.f) << 16)
                | ((unsigned)f2e4m3(l1.w * w1.w * 1024.f) << 24);
    *(uint2*)(KT8 + (size_t)row * 1024 + h0) = make_uint2(u0, u1);
  } else if (g < 8320) {  // BvecB = l0 @ W1b + b1   (32 x 512)
    int b = g - 8192;
    rgemm8_body(512, 32, lab, 2048, W1b, 512, b1, BvecB, 512, b & 31, b >> 5, shf);
  } else if (g < 8449) {
    int b = g - 8320;
    if (b < 32) {  // cv[c] = dot(bsp2, L[c])
      int c = b;
      float a = 0.f;
      for (int k = threadIdx.x; k < 1024; k += 256)
        a = fmaf(bsp2[k], L[(size_t)c * 1024 + k], a);
#pragma unroll
      for (int off = 32; off; off >>= 1) a += __shfl_down(a, off);
      if ((threadIdx.x & 63) == 0) shf[threadIdx.x >> 6] = a;
      __syncthreads();
      if (threadIdx.x == 0) cv[c] = shf[0] + shf[1] + shf[2] + shf[3];
    } else if (b < 64) {  // MmTf -> MmTb bf16
      int i = (b - 32) * 1024 + threadIdx.x * 4;
      float4 v = *(const float4*)(MmTf + i);
      *(ushort4*)(MmTb + i) = make_ushort4(f2b(v.x), f2b(v.y), f2b(v.z), f2b(v.w));
    } else if (b < 96) {  // W2padT[n][d] = n<3 ? W2[d][n] : 0
      int i = (b - 64) * 256 + threadIdx.x;
      int n = i >> 9, d = i & 511;
      W2padT[i] = f2b(n < 3 ? W2[d * 3 + n] : 0.f);
    } else if (b == 96) {  // bsp1 -> bsp1b bf16
      int i = threadIdx.x * 4;
      float4 v = *(const float4*)(bsp1 + i);
      *(ushort4*)(bsp1b + i) = make_ushort4(f2b(v.x), f2b(v.y), f2b(v.z), f2b(v.w));
    } else {  // b in [97,129): bt0A[d] = dot(bt[0:1024], W1a[:,d]), K-parallel
      float (*red)[16] = (float(*)[16])shf;
      int tx = threadIdx.x & 15, ty = threadIdx.x >> 4;
      int d = (b - 97) * 16 + tx;
      float a = 0.f;
      for (int k = ty * 64; k < ty * 64 + 64; ++k)
        a = fmaf(bt[k], W1a[(size_t)k * 512 + d], a);
      red[ty][tx] = a;
      __syncthreads();
      if (ty == 0) {
        float s = 0.f;
#pragma unroll
        for (int q = 0; q < 16; ++q) s += red[q][tx];
        bt0A[d] = s;
      }
    }
  } else {  // wfuse: WfuseT8 = fp8x64(W1aT @ Wtb0^T), 128x128 tiles
    int idx = g - 8449;  // 0..31
    int row0 = (idx >> 3) * 128, col0 = (idx & 7) * 128;
    int tid = threadIdx.x;
    int lane = tid & 63, wid = tid >> 6;
    int wr = wid >> 1, wc = wid & 1;
    f32x4 zero4 = {0.f, 0.f, 0.f, 0.f};
    f32x4 acc[4][4];
#pragma unroll
    for (int i = 0; i < 4; ++i)
#pragma unroll
      for (int j = 0; j < 4; ++j) acc[i][j] = zero4;
    int srow = tid >> 3;
    int scol = ((tid & 7) ^ (srow & 7)) * 8;
    const unsigned short* gA = W1aT + (size_t)(row0 + srow) * 1024 + scol;
    const unsigned short* gB = Wtb0 + (size_t)(col0 + srow) * 1024 + scol;
    int fr = lane & 15, hi = lane >> 4;
#define WF_SM(buf) ((unsigned short*)shraw + (buf) * 16384)
#define W_STAGE(buf, kt)                                                     \
    {                                                                        \
      unsigned short* dA = WF_SM(buf) + tid * 8;                             \
      unsigned short* dB = WF_SM(buf) + 8192 + tid * 8;                      \
      _Pragma("unroll")                                                      \
      for (int i2 = 0; i2 < 4; ++i2) {                                       \
        GLOAD_LDS16(gA + (size_t)(i2 * 32) * 1024 + (kt), dA + i2 * 2048);   \
        GLOAD_LDS16(gB + (size_t)(i2 * 32) * 1024 + (kt), dB + i2 * 2048);   \
      }                                                                      \
    }
    W_STAGE(0, 0);
    for (int t = 0; t < 16; ++t) {
      if (t + 1 < 16) {
        W_STAGE((t + 1) & 1, (t + 1) << 6);
        asm volatile("s_waitcnt vmcnt(8)" ::: "memory");
      } else {
        asm volatile("s_waitcnt vmcnt(0)" ::: "memory");
      }
      __builtin_amdgcn_sched_barrier(0);
      __builtin_amdgcn_s_barrier();
      __builtin_amdgcn_sched_barrier(0);
      const unsigned short* As = WF_SM(t & 1);
      const unsigned short* Bs = As + 8192;
      bf16x8 af[4][2], bfr[4][2];
#pragma unroll
      for (int mi = 0; mi < 4; ++mi) {
        int rl = wr * 64 + mi * 16 + fr;
#pragma unroll
        for (int kk = 0; kk < 2; ++kk)
          af[mi][kk] = *(const bf16x8*)&As[rl * 64 + (((kk << 2) | hi) ^ (rl & 7)) * 8];
      }
#pragma unroll
      for (int ni = 0; ni < 4; ++ni) {
        int rl = wc * 64 + ni * 16 + fr;
#pragma unroll
        for (int kk = 0; kk < 2; ++kk)
          bfr[ni][kk] = *(const bf16x8*)&Bs[rl * 64 + (((kk << 2) | hi) ^ (rl & 7)) * 8];
      }
#pragma unroll
      for (int kk = 0; kk < 2; ++kk)
#pragma unroll
        for (int mi = 0; mi < 4; ++mi)
#pragma unroll
          for (int ni = 0; ni < 4; ++ni)
            acc[mi][ni] = __builtin_amdgcn_mfma_f32_16x16x32_bf16(af[mi][kk], bfr[ni][kk],
                                                                  acc[mi][ni], 0, 0, 0);
      __builtin_amdgcn_sched_barrier(0);
      __builtin_amdgcn_s_barrier();
    }
#undef W_STAGE
#undef WF_SM
    int rbase = row0 + wr * 64 + (hi << 2);
    int cbase = col0 + wc * 64 + fr;
#pragma unroll
    for (int mi = 0; mi < 4; ++mi)
#pragma unroll
      for (int ni = 0; ni < 4; ++ni) {
        int ccol = cbase + ni * 16;
#pragma unroll
        for (int j = 0; j < 4; ++j) {
          int r = rbase + mi * 16 + j;
          WfuseT8[(size_t)r * 1024 + ccol] = f2e4m3(acc[mi][ni][j] * 64.f);
        }
      }
  }
}

// ---------- fgemm: fp8 K=128 merged GEMM [t1 | UV | Avec], N=3584 ----------
__global__ __launch_bounds__(256) void fgemm_k(
    const unsigned char* __restrict__ A, const unsigned char* __restrict__ BT,
    float* __restrict__ Avec, unsigned char* __restrict__ t1f8,
    unsigned short* __restrict__ UVb,
    const float* __restrict__ bt, const float* __restrict__ bt0A) {
  __shared__ __align__(16) unsigned char smem[2][32768];
  int tid = threadIdx.x;
  int lane = tid & 63, wid = tid >> 6;
  int wr = wid >> 1, wc = wid & 1;
  int row0 = blockIdx.y * 128, col0 = blockIdx.x * 128;
  f32x4 zero4 = {0.f, 0.f, 0.f, 0.f};
  f32x4 acc[4][4];
#pragma unroll
  for (int i = 0; i < 4; ++i)
#pragma unroll
    for (int j = 0; j < 4; ++j) acc[i][j] = zero4;
  int srow = tid >> 3;
  int s2 = (tid & 7) ^ (srow & 7);
  int scolB = (((s2 << 1) | (s2 >> 2)) & 7) * 16;
  const unsigned char* gA = A + (size_t)(row0 + srow) * 1024 + scolB;
  const unsigned char* gB = BT + (size_t)(col0 + srow) * 1024 + scolB;
  int fr = lane & 15, hi = lane >> 4;
#define F_STAGE(buf, ktB)                                                    \
  {                                                                          \
    unsigned char* dA = smem[buf] + tid * 16;                                \
    unsigned char* dB = smem[buf] + 16384 + tid * 16;                        \
    _Pragma("unroll")                                                        \
    for (int i2 = 0; i2 < 4; ++i2) {                                         \
      GLOAD_LDS16(gA + (size_t)(i2 * 32) * 1024 + (ktB), dA + i2 * 4096);    \
      GLOAD_LDS16(gB + (size_t)(i2 * 32) * 1024 + (ktB), dB + i2 * 4096);    \
    }                                                                        \
  }
  F_STAGE(0, 0);
  for (int t = 0; t < 8; ++t) {
    if (t + 1 < 8) {
      F_STAGE((t + 1) & 1, (t + 1) * 128);
      asm volatile("s_waitcnt vmcnt(8)" ::: "memory");
    } else {
      asm volatile("s_waitcnt vmcnt(0)" ::: "memory");
    }
    __builtin_amdgcn_sched_barrier(0);
    __builtin_amdgcn_s_barrier();
    __builtin_amdgcn_sched_barrier(0);
    const unsigned char* As = smem[t & 1];
    const unsigned char* Bs = smem[t & 1] + 16384;
    i32x8 af[4], bfr[4];
#pragma unroll
    for (int mi = 0; mi < 4; ++mi) {
      int rl = wr * 64 + mi * 16 + fr;
      i32x4 lo = *(const i32x4*)&As[rl * 128 + ((hi ^ (rl & 7)) * 16)];
      i32x4 h2 = *(const i32x4*)&As[rl * 128 + (((4 + hi) ^ (rl & 7)) * 16)];
      af[mi][0] = lo[0]; af[mi][1] = lo[1]; af[mi][2] = lo[2]; af[mi][3] = lo[3];
      af[mi][4] = h2[0]; af[mi][5] = h2[1]; af[mi][6] = h2[2]; af[mi][7] = h2[3];
    }
#pragma unroll
    for (int ni = 0; ni < 4; ++ni) {
      int rl = wc * 64 + ni * 16 + fr;
      i32x4 lo = *(const i32x4*)&Bs[rl * 128 + ((hi ^ (rl & 7)) * 16)];
      i32x4 h2 = *(const i32x4*)&Bs[rl * 128 + (((4 + hi) ^ (rl & 7)) * 16)];
      bfr[ni][0] = lo[0]; bfr[ni][1] = lo[1]; bfr[ni][2] = lo[2]; bfr[ni][3] = lo[3];
      bfr[ni][4] = h2[0]; bfr[ni][5] = h2[1]; bfr[ni][6] = h2[2]; bfr[ni][7] = h2[3];
    }
#pragma unroll
    for (int mi = 0; mi < 4; ++mi)
#pragma unroll
      for (int ni = 0; ni < 4; ++ni)
        acc[mi][ni] = __builtin_amdgcn_mfma_scale_f32_16x16x128_f8f6f4(
            af[mi], bfr[ni], acc[mi][ni], 0, 0, 0, 127u, 0, 127u);
    __builtin_amdgcn_sched_barrier(0);
    __builtin_amdgcn_s_barrier();
  }
#undef F_STAGE
  const float inv = 0.0009765625f;  // 2^-10 (16 * 64)
  int rbase = row0 + wr * 64 + (hi << 2);
  int cbase = col0 + wc * 64 + fr;
#pragma unroll
  for (int mi = 0; mi < 4; ++mi)
#pragma unroll
    for (int ni = 0; ni < 4; ++ni) {
      int ccol = cbase + ni * 16;
#pragma unroll
      for (int j = 0; j < 4; ++j) {
        int r = rbase + mi * 16 + j;
        float v = acc[mi][ni][j] * inv;
        if (ccol < 1024) {
          t1f8[(size_t)r * 1024 + ccol] = f2e4m3((v + bt[1024 + ccol]) * 16.f);
        } else if (ccol < 3072) {
          UVb[(size_t)r * 2048 + (ccol - 1024)] = f2b(v);
        } else {
          Avec[(size_t)r * 512 + (ccol - 3072)] = v + bt0A[ccol - 3072];
        }
      }
    }
}

// ---------- E-GEMM: 128² tile, MX-fp8 K=128, L2-exact block order ----------
// per XCD: 8 passes of {2 cb-panels x 16 rb} -> L2 set = 2MB B + 2MB A.
__global__ __launch_bounds__(256) void egemm_k(
    const unsigned char* __restrict__ A,   // t1f8 (x16)
    const unsigned char* __restrict__ BT,  // KT8 (x1024)
    const float* __restrict__ avec, const float* __restrict__ bvec,
    const unsigned short* __restrict__ w2t, float* __restrict__ sPart) {
  __shared__ __align__(16) unsigned char smem[2][32768];
  int tid = threadIdx.x;
  int lane = tid & 63, wid = tid >> 6;
  int wr = wid >> 1, wc = wid & 1;
  int bid = blockIdx.x;
  int xcd = bid & 7, ii = bid >> 3;        // ii in [0,256) per xcd
  int cbp = ii >> 5;                       // 0..7  (pair of col-panels)
  int inner = ii & 31;
  int rb = inner >> 1;                     // 0..15
  int cb = xcd * 16 + cbp * 2 + (inner & 1);
  int row0 = rb * 128, col0 = cb * 128, cbq = cb & 3;

  f32x4 zero4 = {0.f, 0.f, 0.f, 0.f};
  f32x4 acc[4][4];
#pragma unroll
  for (int i = 0; i < 4; ++i)
#pragma unroll
    for (int j = 0; j < 4; ++j) acc[i][j] = zero4;

  int srow = tid >> 3;
  int s2 = (tid & 7) ^ (srow & 7);
  int scolB = (((s2 << 1) | (s2 >> 2)) & 7) * 16;
  const unsigned char* gA = A + (size_t)(row0 + srow) * 1024 + scolB;
  const unsigned char* gB = BT + (size_t)(col0 + srow) * 1024 + scolB;

  int fr = lane & 15, hi = lane >> 4;

#define E_STAGE(buf, ktB)                                                    \
  {                                                                          \
    unsigned char* dA = smem[buf] + tid * 16;                                \
    unsigned char* dB = smem[buf] + 16384 + tid * 16;                        \
    _Pragma("unroll")                                                        \
    for (int i2 = 0; i2 < 4; ++i2) {                                         \
      GLOAD_LDS16(gA + (size_t)(i2 * 32) * 1024 + (ktB), dA + i2 * 4096);    \
      GLOAD_LDS16(gB + (size_t)(i2 * 32) * 1024 + (ktB), dB + i2 * 4096);    \
    }                                                                        \
  }

  E_STAGE(0, 0);

  for (int t = 0; t < 8; ++t) {
    if (t + 1 < 8) {
      E_STAGE((t + 1) & 1, (t + 1) * 128);
      asm volatile("s_waitcnt vmcnt(8)" ::: "memory");
    } else {
      asm volatile("s_waitcnt vmcnt(0)" ::: "memory");
    }
    __builtin_amdgcn_sched_barrier(0);
    __builtin_amdgcn_s_barrier();
    __builtin_amdgcn_sched_barrier(0);

    const unsigned char* As = smem[t & 1];
    const unsigned char* Bs = smem[t & 1] + 16384;
    i32x8 af[4], bfr[4];
#pragma unroll
    for (int mi = 0; mi < 4; ++mi) {
      int rl = wr * 64 + mi * 16 + fr;
      i32x4 lo = *(const i32x4*)&As[rl * 128 + ((hi ^ (rl & 7)) * 16)];
      i32x4 h2 = *(const i32x4*)&As[rl * 128 + (((4 + hi) ^ (rl & 7)) * 16)];
      af[mi][0] = lo[0]; af[mi][1] = lo[1]; af[mi][2] = lo[2]; af[mi][3] = lo[3];
      af[mi][4] = h2[0]; af[mi][5] = h2[1]; af[mi][6] = h2[2]; af[mi][7] = h2[3];
    }
#pragma unroll
    for (int ni = 0; ni < 4; ++ni) {
      int rl = wc * 64 + ni * 16 + fr;
      i32x4 lo = *(const i32x4*)&Bs[rl * 128 + ((hi ^ (rl & 7)) * 16)];
      i32x4 h2 = *(const i32x4*)&Bs[rl * 128 + (((4 + hi) ^ (rl & 7)) * 16)];
      bfr[ni][0] = lo[0]; bfr[ni][1] = lo[1]; bfr[ni][2] = lo[2]; bfr[ni][3] = lo[3];
      bfr[ni][4] = h2[0]; bfr[ni][5] = h2[1]; bfr[ni][6] = h2[2]; bfr[ni][7] = h2[3];
    }
#pragma unroll
    for (int mi = 0; mi < 4; ++mi)
#pragma unroll
      for (int ni = 0; ni < 4; ++ni)
        acc[mi][ni] = __builtin_amdgcn_mfma_scale_f32_16x16x128_f8f6f4(
            af[mi], bfr[ni], acc[mi][ni], 0, 0, 0, 127u, 0, 127u);
    __builtin_amdgcn_sched_barrier(0);
    __builtin_amdgcn_s_barrier();
  }
#undef E_STAGE

  // ---- epilogue: h -> swizzled LDS -> W2 MFMA ----
  unsigned short* hsm = (unsigned short*)&smem[0][0];
  int cc = col0 >> 9;
  int dg0 = col0 & 511;
  const float inv = 6.103515625e-05f;  // 2^-14 (16 * 1024)
#pragma unroll
  for (int mi = 0; mi < 4; ++mi) {
#pragma unroll
    for (int j = 0; j < 4; ++j) {
      int rl = wr * 64 + hi * 4 + mi * 16 + j;
      const float* avp = avec + (size_t)(row0 + rl) * 512 + dg0;
      const float* bvp = bvec + (size_t)cc * 512 + dg0;
#pragma unroll
      for (int ni = 0; ni < 4; ++ni) {
        int cl = wc * 64 + ni * 16 + fr;
        float v = acc[mi][ni][j] * inv + avp[cl] + bvp[cl];
        v = fmaxf(v, 0.f);
        int slot = cl >> 3;
        hsm[rl * 128 + (((slot ^ rl) & 7) << 3) + (slot & 8) * 8 + (cl & 7)] = f2b(v);
      }
    }
  }
  __syncthreads();
  f32x4 s0 = zero4, s1 = zero4;
  int r0l = wid * 32 + fr;
  int r1l = wid * 32 + 16 + fr;
#pragma unroll
  for (int kt2 = 0; kt2 < 4; ++kt2) {
    int slot = kt2 * 4 + hi;
    bf16x8 a0 = *(const bf16x8*)&hsm[r0l * 128 + (((slot ^ r0l) & 7) << 3) + (slot & 8) * 8];
    bf16x8 a1 = *(const bf16x8*)&hsm[r1l * 128 + (((slot ^ r1l) & 7) << 3) + (slot & 8) * 8];
    bf16x8 b = *(const bf16x8*)&w2t[(size_t)fr * 512 + dg0 + kt2 * 32 + hi * 8];
    s0 = __builtin_amdgcn_mfma_f32_16x16x32_bf16(a0, b, s0, 0, 0, 0);
    s1 = __builtin_amdgcn_mfma_f32_16x16x32_bf16(a1, b, s1, 0, 0, 0);
  }
  if (fr < 3) {
    float* sp = sPart + ((size_t)cbq * 2048 + row0) * 96 + cc * 3 + fr;
#pragma unroll
    for (int j = 0; j < 4; ++j) {
      sp[(size_t)(wid * 32 + hi * 4 + j) * 96] = s0[j];
      sp[(size_t)(wid * 32 + 16 + hi * 4 + j) * 96] = s1[j];
    }
  }
}

// ---------- fold 4 score slices + b2, then is_start/is_end ----------
__global__ __launch_bounds__(256) void foldmask_k(const float* __restrict__ part,
    const float* __restrict__ b2, float* __restrict__ outS,
    int* __restrict__ is_s, int* __restrict__ is_e) {
  __shared__ float sc[192];
  int b = blockIdx.x;
  int i = threadIdx.x;
  if (i < 192) {
    int idx = b * 192 + i;
    float s = b2[i % 3] + part[idx] + part[196608 + idx] +
              part[2 * 196608 + idx] + part[3 * 196608 + idx];
    outS[idx] = s;
    sc[i] = s;
  }
  __syncthreads();
  if (i < 2) {
    int s = 0, e = 0;
#pragma unroll
    for (int c = 0; c < 32; ++c) {
      s |= (sc[i * 96 + c * 3 + 0] >= 0.f);
      e |= (sc[i * 96 + c * 3 + 1] >= 0.f);
    }
    is_s[2 * b + i] = s;
    is_e[2 * b + i] = e;
  }
}

// ---------- fused span: 16 spans/wave, barrier-free, 2-step unrolled ----------
__global__ __launch_bounds__(256) void spanfuse_k(
    const unsigned short* __restrict__ UVb, const unsigned short* __restrict__ bsp1b,
    const unsigned short* __restrict__ MmTb, const float* __restrict__ cvv,
    const int* __restrict__ is_s, const int* __restrict__ is_e,
    float* __restrict__ outIdx, float* __restrict__ outMask,
    float* __restrict__ outLog) {
  __shared__ __align__(16) unsigned short Rs[4][2][16][32];  // 8 KB
  int tid = threadIdx.x, lane = tid & 63, w = tid >> 6;
  int fr = lane & 15, hi = lane >> 4;
  int row = lane >> 2, q = lane & 3;
  int n = blockIdx.x * 64 + w * 16 + row;
  int wi = n / MAXW;
  int j = n - wi * MAXW;
  int er = wi + j;
  int valid = er < W_WORDS;
  int e = valid ? er : (W_WORDS - 1);
  int mask = (valid && is_s[wi] && is_e[e]) ? 1 : 0;
  if (q == 0) {
    outIdx[2 * n] = (float)wi;
    outIdx[2 * n + 1] = (float)e;
    outMask[n] = (float)mask;
  }
  int si = mask ? wi : 0, ei = mask ? e : 0;
  const unsigned short* Up = UVb + (size_t)si * 2048 + q * 8;
  const unsigned short* Vp = UVb + (size_t)ei * 2048 + 1024 + q * 8;
  const unsigned short* bp = bsp1b + q * 8;
  const unsigned short* M0 = MmTb + (size_t)fr * 1024 + hi * 8;
  const unsigned short* M1 = MmTb + (size_t)(16 + fr) * 1024 + hi * 8;
  unsigned short* wRs0 = &Rs[w][0][0][0];
  unsigned short* wRs1 = &Rs[w][1][0][0];
  int wslot = (q ^ (row & 3)) * 8;
  int rslot = ((hi ^ (fr & 3)) & 3) * 8;
  f32x4 zero4 = {0.f, 0.f, 0.f, 0.f};
  f32x4 a0 = zero4, a1 = zero4;

  bf16x8 u0 = *(const bf16x8*)Up,        v0 = *(const bf16x8*)Vp;
  bf16x8 b0 = *(const bf16x8*)bp;
  bf16x8 u1 = *(const bf16x8*)(Up + 32), v1 = *(const bf16x8*)(Vp + 32);
  bf16x8 b1v = *(const bf16x8*)(bp + 32);
  bf16x8 f00 = *(const bf16x8*)M0,        f10 = *(const bf16x8*)M1;
  bf16x8 f01 = *(const bf16x8*)(M0 + 32), f11 = *(const bf16x8*)(M1 + 32);

  for (int kt = 0; kt < 32; kt += 2) {
    int ka = ((kt + 2) & 31) * 32, kb = ((kt + 3) & 31) * 32;
    bf16x8 nu0 = *(const bf16x8*)(Up + ka), nv0 = *(const bf16x8*)(Vp + ka);
    bf16x8 nb0 = *(const bf16x8*)(bp + ka);
    bf16x8 nu1 = *(const bf16x8*)(Up + kb), nv1 = *(const bf16x8*)(Vp + kb);
    bf16x8 nb1 = *(const bf16x8*)(bp + kb);
    bf16x8 nf00 = *(const bf16x8*)(M0 + ka), nf10 = *(const bf16x8*)(M1 + ka);
    bf16x8 nf01 = *(const bf16x8*)(M0 + kb), nf11 = *(const bf16x8*)(M1 + kb);

    bf16x8 o0, o1;
#pragma unroll
    for (int i = 0; i < 8; ++i) {
      o0[i] = (short)f2b(fmaxf(b2f((unsigned short)u0[i]) + b2f((unsigned short)v0[i]) +
                               b2f((unsigned short)b0[i]), 0.f));
      o1[i] = (short)f2b(fmaxf(b2f((unsigned short)u1[i]) + b2f((unsigned short)v1[i]) +
                               b2f((unsigned short)b1v[i]), 0.f));
    }
    *(bf16x8*)&wRs0[row * 32 + wslot] = o0;
    *(bf16x8*)&wRs1[row * 32 + wslot] = o1;
    asm volatile("s_waitcnt lgkmcnt(0)" ::: "memory");
    bf16x8 fa0 = *(const bf16x8*)&wRs0[fr * 32 + rslot];
    bf16x8 fa1 = *(const bf16x8*)&wRs1[fr * 32 + rslot];
    a0 = __builtin_amdgcn_mfma_f32_16x16x32_bf16(fa0, f00, a0, 0, 0, 0);
    a1 = __builtin_amdgcn_mfma_f32_16x16x32_bf16(fa0, f10, a1, 0, 0, 0);
    a0 = __builtin_amdgcn_mfma_f32_16x16x32_bf16(fa1, f01, a0, 0, 0, 0);
    a1 = __builtin_amdgcn_mfma_f32_16x16x32_bf16(fa1, f11, a1, 0, 0, 0);
    u0 = nu0; v0 = nv0; b0 = nb0;
    u1 = nu1; v1 = nv1; b1v = nb1;
    f00 = nf00; f10 = nf10; f01 = nf01; f11 = nf11;
  }

  int n0 = blockIdx.x * 64 + w * 16;
  float c0 = cvv[fr], c1 = cvv[16 + fr];
#pragma unroll
  for (int jj = 0; jj < 4; ++jj) {
    int nn = n0 + hi * 4 + jj;
    outLog[(size_t)nn * 32 + fr] = a0[jj] + c0;
    outLog[(size_t)nn * 32 + 16 + fr] = a1[jj] + c1;
  }
}

extern "C" void kernel_launch(void* const* d_in, const int* in_sizes, int n_in,
                              void* d_out, int out_size, void* d_ws, size_t ws_size,
                              hipStream_t stream) {
  const float* hs   = (const float*)d_in[0];
  const int*   wm   = (const int*)d_in[1];
  const float* L    = (const float*)d_in[2];
  const float* Wt   = (const float*)d_in[3];
  const float* bt   = (const float*)d_in[4];
  const float* Wl   = (const float*)d_in[5];
  const float* bl   = (const float*)d_in[6];
  const float* W1a  = (const float*)d_in[7];
  const float* W1b  = (const float*)d_in[8];
  const float* W1c  = (const float*)d_in[9];
  const float* b1   = (const float*)d_in[10];
  const float* W2   = (const float*)d_in[11];
  const float* b2   = (const float*)d_in[12];
  const float* Wsp1 = (const float*)d_in[13];
  const float* bsp1 = (const float*)d_in[14];
  const float* Wsp2 = (const float*)d_in[15];
  const float* bsp2 = (const float*)d_in[16];

  char* p = (char*)d_ws;
  auto alloc = [&p](size_t bytes) {
    char* r = p;
    p += (bytes + 255) & ~(size_t)255;
    return r;
  };
  unsigned char*  we8    = (unsigned char*)alloc((size_t)2048 * 1024);
  // WtT8, Wsp1Tc8, WfuseT8 MUST be adjacent: merged BT (3584 x 1024 fp8)
  unsigned char*  WtT8    = (unsigned char*)alloc((size_t)1024 * 1024);
  unsigned char*  Wsp1Tc8 = (unsigned char*)alloc((size_t)2048 * 1024);
  unsigned char*  WfuseT8 = (unsigned char*)alloc((size_t)512 * 1024);
  unsigned char*  t1f8   = (unsigned char*)alloc((size_t)2048 * 1024);
  float*          lab    = (float*)alloc((size_t)32 * 2048 * 4);
  unsigned short* W1aT   = (unsigned short*)alloc((size_t)512 * 1024 * 2);
  unsigned short* Wtb0   = (unsigned short*)alloc((size_t)1024 * 1024 * 2);
  float*          Avec   = (float*)alloc((size_t)2048 * 512 * 4);
  float*          BvecB  = (float*)alloc((size_t)32 * 512 * 4);
  float*          bt0A   = (float*)alloc(512 * 4);
  float*          W1cT   = (float*)alloc((size_t)512 * 1024 * 4);
  unsigned char*  KT8    = (unsigned char*)alloc((size_t)16384 * 1024);
  float*          sPart  = (float*)alloc((size_t)4 * 2048 * 96 * 4);
  int*            is_s   = (int*)alloc(2048 * 4);
  int*            is_e   = (int*)alloc(2048 * 4);
  unsigned short* UVb    = (unsigned short*)alloc((size_t)2048 * 2048 * 2);
  float*          Wsp2T  = (float*)alloc((size_t)1024 * 1024 * 4);
  float*          MmTf   = (float*)alloc((size_t)32 * 1024 * 4);
  unsigned short* MmTb   = (unsigned short*)alloc((size_t)32 * 1024 * 2);
  float*          cv     = (float*)alloc(32 * 4);
  unsigned short* W2padT = (unsigned short*)alloc((size_t)16 * 512 * 2);
  unsigned short* bsp1b  = (unsigned short*)alloc((size_t)1024 * 2);

  float* outS    = (float*)d_out;
  float* outIdx  = outS + (size_t)2048 * 32 * 3;
  float* outMask = outIdx + (size_t)NSPAN * 2;
  float* outLog  = outMask + NSPAN;

  // transposes (fp8 weights) + gather (fp8 we) + Wtb0 in one launch
  mega0_k<<<dim3(96, 32, 8), dim3(32, 8), 0, stream>>>(
      hs, wm, we8, Wt, W1a, Wsp1, W1c, Wsp2, WtT8, W1aT, Wsp1Tc8, W1cT, Wsp2T, Wtb0);

  // lab = L@Wl+bl and MmTf = L@Wsp2T
  rgemm8z_k<<<dim3(128, 4, 2), 256, 0, stream>>>(L, Wl, bl, lab, Wsp2T, MmTf);

  // kmat(fp8) + BvecB + misc + bt0A + wfuse tiles in one launch
  mega1_k<<<8481, 256, 0, stream>>>(lab, W1cT, KT8, W1b, b1, BvecB,
                                    bsp2, L, cv, MmTf, MmTb, W2, W2padT, bsp1, bsp1b,
                                    bt, W1a, bt0A, W1aT, Wtb0, WfuseT8);

  // merged fp8: [t1 | UV | Avec] = we @ [Wt_hi | Wsp1 | Wfuse]  (N = 3584)
  fgemm_k<<<dim3(28, 16), 256, 0, stream>>>(we8, WtT8, Avec, t1f8, UVb, bt, bt0A);

  // E-GEMM (MX-fp8 K=128, L2-exact order) + fused score partials
  egemm_k<<<2048, 256, 0, stream>>>(t1f8, KT8, Avec, BvecB, W2padT, sPart);

  // fold scores + masks
  foldmask_k<<<1024, 256, 0, stream>>>(sPart, b2, outS, is_s, is_e);

  // fused span: 16 spans/wave, barrier-free, 2-step unrolled
  spanfuse_k<<<384, 256, 0, stream>>>(UVb, bsp1b, MmTb, cv, is_s, is_e,
                                      outIdx, outMask, outLog);
}

// Round 16
// 168.433 us; speedup vs baseline: 1.1569x; 1.1569x over previous
//
#include <hip/hip_runtime.h>
#include <hip/hip_bf16.h>

#define W_WORDS 2048
#define H_DIM   1024
#define C_LAB   32
#define HID_D   512
#define MAXW    12
#define NSPAN   (W_WORDS * MAXW)

typedef __attribute__((ext_vector_type(8))) short bf16x8;
typedef __attribute__((ext_vector_type(4))) float f32x4;
typedef __attribute__((ext_vector_type(4))) int i32x4;
typedef __attribute__((ext_vector_type(8))) int i32x8;

__device__ __forceinline__ unsigned short f2b(float x) {
  union { float f; unsigned int i; } v; v.f = x;
  unsigned int r = v.i + 0x7FFFu + ((v.i >> 16) & 1u);
  return (unsigned short)(r >> 16);
}
__device__ __forceinline__ float b2f(unsigned short b) {
  union { float f; unsigned int i; } v; v.i = ((unsigned int)b) << 16;
  return v.f;
}

// f32 -> OCP e4m3fn, RNE, satfinite(448)
__device__ __forceinline__ unsigned char f2e4m3(float x) {
  union { float f; unsigned u; } v; v.f = x;
  unsigned sign = (v.u >> 31) << 7;
  v.u &= 0x7FFFFFFFu;
  if (v.f > 448.f) v.f = 448.f;
  int e8 = (int)(v.u >> 23) - 120;
  unsigned r;
  if (e8 >= 1) {
    unsigned m = v.u & 0x7FFFFFu;
    unsigned keep = m >> 20;
    unsigned rest = m & 0xFFFFFu;
    keep += (rest > 0x80000u) || (rest == 0x80000u && (keep & 1u));
    if (keep == 8u) { keep = 0u; ++e8; }
    if (e8 >= 16) { e8 = 15; keep = 6u; }
    else if (e8 == 15 && keep == 7u) keep = 6u;  // avoid NaN encoding
    r = (unsigned)((e8 << 3) | keep);
  } else {
    int m = (int)(v.f * 512.f + 0.5f);
    r = (m >= 8) ? 0x08u : (unsigned)m;
  }
  return (unsigned char)(r | sign);
}

#define GLOAD_LDS16(g, l)                                                    \
  __builtin_amdgcn_global_load_lds(                                          \
      (const __attribute__((address_space(1))) unsigned int*)(g),            \
      (__attribute__((address_space(3))) unsigned int*)(l), 16, 0, 0)

// ---------- mega0: transposes (z<6) + gather fp8 (z==6) + Wtb0 cvt (z==7) ----------
__global__ void mega0_k(const float* __restrict__ hs, const int* __restrict__ wm,
    unsigned char* __restrict__ we8,
    const float* __restrict__ Wt, const float* __restrict__ W1a,
    const float* __restrict__ Wsp1, const float* __restrict__ W1c,
    const float* __restrict__ Wsp2,
    unsigned char* __restrict__ WtT8, unsigned short* __restrict__ W1aT,
    unsigned char* __restrict__ Wsp1Tc8, float* __restrict__ W1cT,
    float* __restrict__ Wsp2T, unsigned short* __restrict__ Wtb0) {
  if (blockIdx.z == 6) {  // gather: we8[m-1] = fp8(hs[t] * 16)
    int t = blockIdx.y * 96 + blockIdx.x;
    int m = wm[t];
    if (m <= 0) return;
    const float* src = hs + (size_t)t * H_DIM;
    unsigned char* dst = we8 + (size_t)(m - 1) * H_DIM;
    int i = (threadIdx.y * 32 + threadIdx.x) * 4;
    float4 v = *(const float4*)(src + i);
    unsigned u = (unsigned)f2e4m3(v.x * 16.f)
               | ((unsigned)f2e4m3(v.y * 16.f) << 8)
               | ((unsigned)f2e4m3(v.z * 16.f) << 16)
               | ((unsigned)f2e4m3(v.w * 16.f) << 24);
    *(unsigned*)(dst + i) = u;
    return;
  }
  int c0 = blockIdx.x * 32, r0 = blockIdx.y * 32;
  if (blockIdx.z == 7) {  // Wtb0[h][g] = bf16(Wt[h][g]), g<1024
    if (c0 >= 1024) return;
    for (int i = threadIdx.y; i < 32; i += 8)
      Wtb0[(size_t)(r0 + i) * 1024 + c0 + threadIdx.x] =
          f2b(Wt[(size_t)(r0 + i) * 2048 + c0 + threadIdx.x]);
    return;
  }
  const float* in;
  void* out;
  int R, C, ld, mode;  // mode: 0=f32, 1=bf16, 2=fp8 x64
  switch (blockIdx.z) {
    case 0: in = Wt + 1024; out = WtT8; R = 1024; C = 1024; ld = 2048; mode = 2; break;
    case 1: in = W1a;  out = W1aT;   R = 1024; C = 512;  ld = 512;  mode = 1; break;
    case 2: in = Wsp1; out = Wsp1Tc8; R = 1024; C = 1024; ld = 1024; mode = 2; break;
    case 3: in = Wsp1 + 1048576; out = Wsp1Tc8 + 1048576; R = 1024; C = 1024; ld = 1024; mode = 2; break;
    case 4: in = W1c;  out = W1cT;   R = 1024; C = 512;  ld = 512;  mode = 0; break;
    default: in = Wsp2; out = Wsp2T; R = 1024; C = 1024; ld = 1024; mode = 0; break;
  }
  if (c0 >= C || r0 >= R) return;
  __shared__ float tile[32][33];
  for (int i = threadIdx.y; i < 32; i += 8)
    tile[i][threadIdx.x] = in[(size_t)(r0 + i) * ld + c0 + threadIdx.x];
  __syncthreads();
  if (mode == 2) {
    unsigned char* o = (unsigned char*)out;
    for (int i = threadIdx.y; i < 32; i += 8)
      o[(size_t)(c0 + i) * R + r0 + threadIdx.x] = f2e4m3(tile[threadIdx.x][i] * 64.f);
  } else if (mode == 1) {
    unsigned short* o = (unsigned short*)out;
    for (int i = threadIdx.y; i < 32; i += 8)
      o[(size_t)(c0 + i) * R + r0 + threadIdx.x] = f2b(tile[threadIdx.x][i]);
  } else {
    float* o = (float*)out;
    for (int i = threadIdx.y; i < 32; i += 8)
      o[(size_t)(c0 + i) * R + r0 + threadIdx.x] = tile[threadIdx.x][i];
  }
}

// ---------- small GEMM body, 8 A-rows per block ----------
__device__ __forceinline__ void rgemm8_body(int N, int M,
    const float* __restrict__ A, int lda, const float* __restrict__ B, int ldb,
    const float* __restrict__ bias, float* __restrict__ out, int ldc,
    int bx, int by, float* shf) {
  float (*Asm)[1024] = (float(*)[1024])shf;
  float (*red)[16][8] = (float(*)[16][8])(shf + 8192);
  int m0 = by * 8;
  for (int idx = threadIdx.x; idx < 8 * 1024; idx += 256) {
    int mm = idx >> 10, kk = idx & 1023;
    Asm[mm][kk] = (m0 + mm < M) ? A[(size_t)(m0 + mm) * lda + kk] : 0.f;
  }
  __syncthreads();
  int tx = threadIdx.x & 15, ty = threadIdx.x >> 4;
  int n = bx * 16 + tx;
  float acc[8] = {0.f, 0.f, 0.f, 0.f, 0.f, 0.f, 0.f, 0.f};
  if (n < N) {
    for (int k = ty * 64; k < ty * 64 + 64; ++k) {
      float bv = B[(size_t)k * ldb + n];
#pragma unroll
      for (int mm = 0; mm < 8; ++mm) acc[mm] = fmaf(Asm[mm][k], bv, acc[mm]);
    }
  }
#pragma unroll
  for (int mm = 0; mm < 8; ++mm) red[ty][tx][mm] = acc[mm];
  __syncthreads();
  if (ty < 8 && n < N && m0 + ty < M) {
    float s = 0.f;
#pragma unroll
    for (int q = 0; q < 16; ++q) s += red[q][tx][ty];
    if (bias) s += bias[n];
    out[(size_t)(m0 + ty) * ldc + n] = s;
  }
}

// lab = L@Wl+bl (z=0) and MmTf = L@Wsp2T (z=1)
__global__ __launch_bounds__(256) void rgemm8z_k(
    const float* __restrict__ L, const float* __restrict__ Wl,
    const float* __restrict__ bl, float* __restrict__ lab,
    const float* __restrict__ Wsp2T, float* __restrict__ MmTf) {
  __shared__ float shf[10240];
  if (blockIdx.z == 0) {
    rgemm8_body(2048, 32, L, 1024, Wl, 2048, bl, lab, 2048, blockIdx.x, blockIdx.y, shf);
  } else {
    if (blockIdx.x >= 64) return;
    rgemm8_body(1024, 32, L, 1024, Wsp2T, 1024, nullptr, MmTf, 1024,
                blockIdx.x, blockIdx.y, shf);
  }
}

// ---------- mega1: kmat(reg-resident W1c) + BvecB + misc + bt0A + wfuse ----------
// kmat: g<256, block = 2 d-rows x all 32 c -> W1cT read once (2MB total)
__global__ __launch_bounds__(256) void mega1_k(
    const float* __restrict__ lab, const float* __restrict__ W1cT,
    unsigned char* __restrict__ KT8,
    const float* __restrict__ W1b, const float* __restrict__ b1,
    float* __restrict__ BvecB,
    const float* __restrict__ bsp2, const float* __restrict__ L,
    float* __restrict__ cv, const float* __restrict__ MmTf,
    unsigned short* __restrict__ MmTb, const float* __restrict__ W2,
    unsigned short* __restrict__ W2padT, const float* __restrict__ bsp1,
    unsigned short* __restrict__ bsp1b,
    const float* __restrict__ bt, const float* __restrict__ W1a,
    float* __restrict__ bt0A,
    const unsigned short* __restrict__ W1aT, const unsigned short* __restrict__ Wtb0,
    unsigned char* __restrict__ WfuseT8) {
  __shared__ __align__(16) unsigned char shraw[65536];
  float* shf = (float*)shraw;
  int g = blockIdx.x;
  if (g < 256) {  // KT8[(c*512+d)][h] = fp8(lab1[c][h] * W1cT[d][h] * 1024)
    int t = threadIdx.x;
    int d = g * 2 + (t >> 7);
    int h0 = (t & 127) * 8;
    const float* wp = W1cT + (size_t)d * 1024 + h0;
    float4 w0 = *(const float4*)wp, w1 = *(const float4*)(wp + 4);
#pragma unroll 4
    for (int c = 0; c < 32; ++c) {
      const float* lp = lab + (size_t)c * 2048 + 1024 + h0;
      float4 l0 = *(const float4*)lp, l1 = *(const float4*)(lp + 4);
      unsigned u0 = (unsigned)f2e4m3(l0.x * w0.x * 1024.f)
                  | ((unsigned)f2e4m3(l0.y * w0.y * 1024.f) << 8)
                  | ((unsigned)f2e4m3(l0.z * w0.z * 1024.f) << 16)
                  | ((unsigned)f2e4m3(l0.w * w0.w * 1024.f) << 24);
      unsigned u1 = (unsigned)f2e4m3(l1.x * w1.x * 1024.f)
                  | ((unsigned)f2e4m3(l1.y * w1.y * 1024.f) << 8)
                  | ((unsigned)f2e4m3(l1.z * w1.z * 1024.f) << 16)
                  | ((unsigned)f2e4m3(l1.w * w1.w * 1024.f) << 24);
      *(uint2*)(KT8 + (size_t)(c * 512 + d) * 1024 + h0) = make_uint2(u0, u1);
    }
  } else if (g < 384) {  // BvecB = l0 @ W1b + b1   (32 x 512)
    int b = g - 256;
    rgemm8_body(512, 32, lab, 2048, W1b, 512, b1, BvecB, 512, b & 31, b >> 5, shf);
  } else if (g < 513) {
    int b = g - 384;
    if (b < 32) {  // cv[c] = dot(bsp2, L[c])
      int c = b;
      float a = 0.f;
      for (int k = threadIdx.x; k < 1024; k += 256)
        a = fmaf(bsp2[k], L[(size_t)c * 1024 + k], a);
#pragma unroll
      for (int off = 32; off; off >>= 1) a += __shfl_down(a, off);
      if ((threadIdx.x & 63) == 0) shf[threadIdx.x >> 6] = a;
      __syncthreads();
      if (threadIdx.x == 0) cv[c] = shf[0] + shf[1] + shf[2] + shf[3];
    } else if (b < 64) {  // MmTf -> MmTb bf16
      int i = (b - 32) * 1024 + threadIdx.x * 4;
      float4 v = *(const float4*)(MmTf + i);
      *(ushort4*)(MmTb + i) = make_ushort4(f2b(v.x), f2b(v.y), f2b(v.z), f2b(v.w));
    } else if (b < 96) {  // W2padT[n][d] = n<3 ? W2[d][n] : 0
      int i = (b - 64) * 256 + threadIdx.x;
      int n = i >> 9, d = i & 511;
      W2padT[i] = f2b(n < 3 ? W2[d * 3 + n] : 0.f);
    } else if (b == 96) {  // bsp1 -> bsp1b bf16
      int i = threadIdx.x * 4;
      float4 v = *(const float4*)(bsp1 + i);
      *(ushort4*)(bsp1b + i) = make_ushort4(f2b(v.x), f2b(v.y), f2b(v.z), f2b(v.w));
    } else {  // b in [97,129): bt0A[d] = dot(bt[0:1024], W1a[:,d]), K-parallel
      float (*red)[16] = (float(*)[16])shf;
      int tx = threadIdx.x & 15, ty = threadIdx.x >> 4;
      int d = (b - 97) * 16 + tx;
      float a = 0.f;
      for (int k = ty * 64; k < ty * 64 + 64; ++k)
        a = fmaf(bt[k], W1a[(size_t)k * 512 + d], a);
      red[ty][tx] = a;
      __syncthreads();
      if (ty == 0) {
        float s = 0.f;
#pragma unroll
        for (int q = 0; q < 16; ++q) s += red[q][tx];
        bt0A[d] = s;
      }
    }
  } else {  // wfuse: WfuseT8 = fp8x64(W1aT @ Wtb0^T), 128x128 tiles
    int idx = g - 513;  // 0..31
    int row0 = (idx >> 3) * 128, col0 = (idx & 7) * 128;
    int tid = threadIdx.x;
    int lane = tid & 63, wid = tid >> 6;
    int wr = wid >> 1, wc = wid & 1;
    f32x4 zero4 = {0.f, 0.f, 0.f, 0.f};
    f32x4 acc[4][4];
#pragma unroll
    for (int i = 0; i < 4; ++i)
#pragma unroll
      for (int j = 0; j < 4; ++j) acc[i][j] = zero4;
    int srow = tid >> 3;
    int scol = ((tid & 7) ^ (srow & 7)) * 8;
    const unsigned short* gA = W1aT + (size_t)(row0 + srow) * 1024 + scol;
    const unsigned short* gB = Wtb0 + (size_t)(col0 + srow) * 1024 + scol;
    int fr = lane & 15, hi = lane >> 4;
#define WF_SM(buf) ((unsigned short*)shraw + (buf) * 16384)
#define W_STAGE(buf, kt)                                                     \
    {                                                                        \
      unsigned short* dA = WF_SM(buf) + tid * 8;                             \
      unsigned short* dB = WF_SM(buf) + 8192 + tid * 8;                      \
      _Pragma("unroll")                                                      \
      for (int i2 = 0; i2 < 4; ++i2) {                                       \
        GLOAD_LDS16(gA + (size_t)(i2 * 32) * 1024 + (kt), dA + i2 * 2048);   \
        GLOAD_LDS16(gB + (size_t)(i2 * 32) * 1024 + (kt), dB + i2 * 2048);   \
      }                                                                      \
    }
    W_STAGE(0, 0);
    for (int t = 0; t < 16; ++t) {
      if (t + 1 < 16) {
        W_STAGE((t + 1) & 1, (t + 1) << 6);
        asm volatile("s_waitcnt vmcnt(8)" ::: "memory");
      } else {
        asm volatile("s_waitcnt vmcnt(0)" ::: "memory");
      }
      __builtin_amdgcn_sched_barrier(0);
      __builtin_amdgcn_s_barrier();
      __builtin_amdgcn_sched_barrier(0);
      const unsigned short* As = WF_SM(t & 1);
      const unsigned short* Bs = As + 8192;
      bf16x8 af[4][2], bfr[4][2];
#pragma unroll
      for (int mi = 0; mi < 4; ++mi) {
        int rl = wr * 64 + mi * 16 + fr;
#pragma unroll
        for (int kk = 0; kk < 2; ++kk)
          af[mi][kk] = *(const bf16x8*)&As[rl * 64 + (((kk << 2) | hi) ^ (rl & 7)) * 8];
      }
#pragma unroll
      for (int ni = 0; ni < 4; ++ni) {
        int rl = wc * 64 + ni * 16 + fr;
#pragma unroll
        for (int kk = 0; kk < 2; ++kk)
          bfr[ni][kk] = *(const bf16x8*)&Bs[rl * 64 + (((kk << 2) | hi) ^ (rl & 7)) * 8];
      }
#pragma unroll
      for (int kk = 0; kk < 2; ++kk)
#pragma unroll
        for (int mi = 0; mi < 4; ++mi)
#pragma unroll
          for (int ni = 0; ni < 4; ++ni)
            acc[mi][ni] = __builtin_amdgcn_mfma_f32_16x16x32_bf16(af[mi][kk], bfr[ni][kk],
                                                                  acc[mi][ni], 0, 0, 0);
      __builtin_amdgcn_sched_barrier(0);
      __builtin_amdgcn_s_barrier();
    }
#undef W_STAGE
#undef WF_SM
    int rbase = row0 + wr * 64 + (hi << 2);
    int cbase = col0 + wc * 64 + fr;
#pragma unroll
    for (int mi = 0; mi < 4; ++mi)
#pragma unroll
      for (int ni = 0; ni < 4; ++ni) {
        int ccol = cbase + ni * 16;
#pragma unroll
        for (int j = 0; j < 4; ++j) {
          int r = rbase + mi * 16 + j;
          WfuseT8[(size_t)r * 1024 + ccol] = f2e4m3(acc[mi][ni][j] * 64.f);
        }
      }
  }
}

// ---------- fgemm: fp8 K=128 merged GEMM [t1 | UV | Avec], N=3584 ----------
__global__ __launch_bounds__(256) void fgemm_k(
    const unsigned char* __restrict__ A, const unsigned char* __restrict__ BT,
    float* __restrict__ Avec, unsigned char* __restrict__ t1f8,
    unsigned short* __restrict__ UVb,
    const float* __restrict__ bt, const float* __restrict__ bt0A) {
  __shared__ __align__(16) unsigned char smem[2][32768];
  int tid = threadIdx.x;
  int lane = tid & 63, wid = tid >> 6;
  int wr = wid >> 1, wc = wid & 1;
  int row0 = blockIdx.y * 128, col0 = blockIdx.x * 128;
  f32x4 zero4 = {0.f, 0.f, 0.f, 0.f};
  f32x4 acc[4][4];
#pragma unroll
  for (int i = 0; i < 4; ++i)
#pragma unroll
    for (int j = 0; j < 4; ++j) acc[i][j] = zero4;
  int srow = tid >> 3;
  int s2 = (tid & 7) ^ (srow & 7);
  int scolB = (((s2 << 1) | (s2 >> 2)) & 7) * 16;
  const unsigned char* gA = A + (size_t)(row0 + srow) * 1024 + scolB;
  const unsigned char* gB = BT + (size_t)(col0 + srow) * 1024 + scolB;
  int fr = lane & 15, hi = lane >> 4;
#define F_STAGE(buf, ktB)                                                    \
  {                                                                          \
    unsigned char* dA = smem[buf] + tid * 16;                                \
    unsigned char* dB = smem[buf] + 16384 + tid * 16;                        \
    _Pragma("unroll")                                                        \
    for (int i2 = 0; i2 < 4; ++i2) {                                         \
      GLOAD_LDS16(gA + (size_t)(i2 * 32) * 1024 + (ktB), dA + i2 * 4096);    \
      GLOAD_LDS16(gB + (size_t)(i2 * 32) * 1024 + (ktB), dB + i2 * 4096);    \
    }                                                                        \
  }
  F_STAGE(0, 0);
  for (int t = 0; t < 8; ++t) {
    if (t + 1 < 8) {
      F_STAGE((t + 1) & 1, (t + 1) * 128);
      asm volatile("s_waitcnt vmcnt(8)" ::: "memory");
    } else {
      asm volatile("s_waitcnt vmcnt(0)" ::: "memory");
    }
    __builtin_amdgcn_sched_barrier(0);
    __builtin_amdgcn_s_barrier();
    __builtin_amdgcn_sched_barrier(0);
    const unsigned char* As = smem[t & 1];
    const unsigned char* Bs = smem[t & 1] + 16384;
    i32x8 af[4], bfr[4];
#pragma unroll
    for (int mi = 0; mi < 4; ++mi) {
      int rl = wr * 64 + mi * 16 + fr;
      i32x4 lo = *(const i32x4*)&As[rl * 128 + ((hi ^ (rl & 7)) * 16)];
      i32x4 h2 = *(const i32x4*)&As[rl * 128 + (((4 + hi) ^ (rl & 7)) * 16)];
      af[mi][0] = lo[0]; af[mi][1] = lo[1]; af[mi][2] = lo[2]; af[mi][3] = lo[3];
      af[mi][4] = h2[0]; af[mi][5] = h2[1]; af[mi][6] = h2[2]; af[mi][7] = h2[3];
    }
#pragma unroll
    for (int ni = 0; ni < 4; ++ni) {
      int rl = wc * 64 + ni * 16 + fr;
      i32x4 lo = *(const i32x4*)&Bs[rl * 128 + ((hi ^ (rl & 7)) * 16)];
      i32x4 h2 = *(const i32x4*)&Bs[rl * 128 + (((4 + hi) ^ (rl & 7)) * 16)];
      bfr[ni][0] = lo[0]; bfr[ni][1] = lo[1]; bfr[ni][2] = lo[2]; bfr[ni][3] = lo[3];
      bfr[ni][4] = h2[0]; bfr[ni][5] = h2[1]; bfr[ni][6] = h2[2]; bfr[ni][7] = h2[3];
    }
#pragma unroll
    for (int mi = 0; mi < 4; ++mi)
#pragma unroll
      for (int ni = 0; ni < 4; ++ni)
        acc[mi][ni] = __builtin_amdgcn_mfma_scale_f32_16x16x128_f8f6f4(
            af[mi], bfr[ni], acc[mi][ni], 0, 0, 0, 127u, 0, 127u);
    __builtin_amdgcn_sched_barrier(0);
    __builtin_amdgcn_s_barrier();
  }
#undef F_STAGE
  const float inv = 0.0009765625f;  // 2^-10 (16 * 64)
  int rbase = row0 + wr * 64 + (hi << 2);
  int cbase = col0 + wc * 64 + fr;
#pragma unroll
  for (int mi = 0; mi < 4; ++mi)
#pragma unroll
    for (int ni = 0; ni < 4; ++ni) {
      int ccol = cbase + ni * 16;
#pragma unroll
      for (int j = 0; j < 4; ++j) {
        int r = rbase + mi * 16 + j;
        float v = acc[mi][ni][j] * inv;
        if (ccol < 1024) {
          t1f8[(size_t)r * 1024 + ccol] = f2e4m3((v + bt[1024 + ccol]) * 16.f);
        } else if (ccol < 3072) {
          UVb[(size_t)r * 2048 + (ccol - 1024)] = f2b(v);
        } else {
          Avec[(size_t)r * 512 + (ccol - 3072)] = v + bt0A[ccol - 3072];
        }
      }
    }
}

// ---------- E-GEMM: 128² tile, MX-fp8 K=128, r14 8x8 supertile order ----------
__global__ __launch_bounds__(256) void egemm_k(
    const unsigned char* __restrict__ A,   // t1f8 (x16)
    const unsigned char* __restrict__ BT,  // KT8 (x1024)
    const float* __restrict__ avec, const float* __restrict__ bvec,
    const unsigned short* __restrict__ w2t, float* __restrict__ sPart) {
  __shared__ __align__(16) unsigned char smem[2][32768];
  int tid = threadIdx.x;
  int lane = tid & 63, wid = tid >> 6;
  int wr = wid >> 1, wc = wid & 1;
  // 8 xcd x (2x2 supergrid of 8rb x 8cb supertiles): r14-proven ordering
  int bid = blockIdx.x;
  int xcd = bid & 7, ii = bid >> 3;
  int sg = ii >> 6, inner = ii & 63;
  int rb = ((sg >> 1) << 3) | (inner & 7);
  int cb = xcd * 16 + (((sg & 1) << 3) | (inner >> 3));
  int row0 = rb * 128, col0 = cb * 128, cbq = cb & 3;

  f32x4 zero4 = {0.f, 0.f, 0.f, 0.f};
  f32x4 acc[4][4];
#pragma unroll
  for (int i = 0; i < 4; ++i)
#pragma unroll
    for (int j = 0; j < 4; ++j) acc[i][j] = zero4;

  int srow = tid >> 3;
  int s2 = (tid & 7) ^ (srow & 7);
  int scolB = (((s2 << 1) | (s2 >> 2)) & 7) * 16;
  const unsigned char* gA = A + (size_t)(row0 + srow) * 1024 + scolB;
  const unsigned char* gB = BT + (size_t)(col0 + srow) * 1024 + scolB;

  int fr = lane & 15, hi = lane >> 4;

#define E_STAGE(buf, ktB)                                                    \
  {                                                                          \
    unsigned char* dA = smem[buf] + tid * 16;                                \
    unsigned char* dB = smem[buf] + 16384 + tid * 16;                        \
    _Pragma("unroll")                                                        \
    for (int i2 = 0; i2 < 4; ++i2) {                                         \
      GLOAD_LDS16(gA + (size_t)(i2 * 32) * 1024 + (ktB), dA + i2 * 4096);    \
      GLOAD_LDS16(gB + (size_t)(i2 * 32) * 1024 + (ktB), dB + i2 * 4096);    \
    }                                                                        \
  }

  E_STAGE(0, 0);

  for (int t = 0; t < 8; ++t) {
    if (t + 1 < 8) {
      E_STAGE((t + 1) & 1, (t + 1) * 128);
      asm volatile("s_waitcnt vmcnt(8)" ::: "memory");
    } else {
      asm volatile("s_waitcnt vmcnt(0)" ::: "memory");
    }
    __builtin_amdgcn_sched_barrier(0);
    __builtin_amdgcn_s_barrier();
    __builtin_amdgcn_sched_barrier(0);

    const unsigned char* As = smem[t & 1];
    const unsigned char* Bs = smem[t & 1] + 16384;
    i32x8 af[4], bfr[4];
#pragma unroll
    for (int mi = 0; mi < 4; ++mi) {
      int rl = wr * 64 + mi * 16 + fr;
      i32x4 lo = *(const i32x4*)&As[rl * 128 + ((hi ^ (rl & 7)) * 16)];
      i32x4 h2 = *(const i32x4*)&As[rl * 128 + (((4 + hi) ^ (rl & 7)) * 16)];
      af[mi][0] = lo[0]; af[mi][1] = lo[1]; af[mi][2] = lo[2]; af[mi][3] = lo[3];
      af[mi][4] = h2[0]; af[mi][5] = h2[1]; af[mi][6] = h2[2]; af[mi][7] = h2[3];
    }
#pragma unroll
    for (int ni = 0; ni < 4; ++ni) {
      int rl = wc * 64 + ni * 16 + fr;
      i32x4 lo = *(const i32x4*)&Bs[rl * 128 + ((hi ^ (rl & 7)) * 16)];
      i32x4 h2 = *(const i32x4*)&Bs[rl * 128 + (((4 + hi) ^ (rl & 7)) * 16)];
      bfr[ni][0] = lo[0]; bfr[ni][1] = lo[1]; bfr[ni][2] = lo[2]; bfr[ni][3] = lo[3];
      bfr[ni][4] = h2[0]; bfr[ni][5] = h2[1]; bfr[ni][6] = h2[2]; bfr[ni][7] = h2[3];
    }
#pragma unroll
    for (int mi = 0; mi < 4; ++mi)
#pragma unroll
      for (int ni = 0; ni < 4; ++ni)
        acc[mi][ni] = __builtin_amdgcn_mfma_scale_f32_16x16x128_f8f6f4(
            af[mi], bfr[ni], acc[mi][ni], 0, 0, 0, 127u, 0, 127u);
    __builtin_amdgcn_sched_barrier(0);
    __builtin_amdgcn_s_barrier();
  }
#undef E_STAGE

  // ---- epilogue: h -> swizzled LDS -> W2 MFMA ----
  unsigned short* hsm = (unsigned short*)&smem[0][0];
  int cc = col0 >> 9;
  int dg0 = col0 & 511;
  const float inv = 6.103515625e-05f;  // 2^-14 (16 * 1024)
#pragma unroll
  for (int mi = 0; mi < 4; ++mi) {
#pragma unroll
    for (int j = 0; j < 4; ++j) {
      int rl = wr * 64 + hi * 4 + mi * 16 + j;
      const float* avp = avec + (size_t)(row0 + rl) * 512 + dg0;
      const float* bvp = bvec + (size_t)cc * 512 + dg0;
#pragma unroll
      for (int ni = 0; ni < 4; ++ni) {
        int cl = wc * 64 + ni * 16 + fr;
        float v = acc[mi][ni][j] * inv + avp[cl] + bvp[cl];
        v = fmaxf(v, 0.f);
        int slot = cl >> 3;
        hsm[rl * 128 + (((slot ^ rl) & 7) << 3) + (slot & 8) * 8 + (cl & 7)] = f2b(v);
      }
    }
  }
  __syncthreads();
  f32x4 s0 = zero4, s1 = zero4;
  int r0l = wid * 32 + fr;
  int r1l = wid * 32 + 16 + fr;
#pragma unroll
  for (int kt2 = 0; kt2 < 4; ++kt2) {
    int slot = kt2 * 4 + hi;
    bf16x8 a0 = *(const bf16x8*)&hsm[r0l * 128 + (((slot ^ r0l) & 7) << 3) + (slot & 8) * 8];
    bf16x8 a1 = *(const bf16x8*)&hsm[r1l * 128 + (((slot ^ r1l) & 7) << 3) + (slot & 8) * 8];
    bf16x8 b = *(const bf16x8*)&w2t[(size_t)fr * 512 + dg0 + kt2 * 32 + hi * 8];
    s0 = __builtin_amdgcn_mfma_f32_16x16x32_bf16(a0, b, s0, 0, 0, 0);
    s1 = __builtin_amdgcn_mfma_f32_16x16x32_bf16(a1, b, s1, 0, 0, 0);
  }
  if (fr < 3) {
    float* sp = sPart + ((size_t)cbq * 2048 + row0) * 96 + cc * 3 + fr;
#pragma unroll
    for (int j = 0; j < 4; ++j) {
      sp[(size_t)(wid * 32 + hi * 4 + j) * 96] = s0[j];
      sp[(size_t)(wid * 32 + 16 + hi * 4 + j) * 96] = s1[j];
    }
  }
}

// ---------- fold 4 score slices + b2, then is_start/is_end ----------
__global__ __launch_bounds__(256) void foldmask_k(const float* __restrict__ part,
    const float* __restrict__ b2, float* __restrict__ outS,
    int* __restrict__ is_s, int* __restrict__ is_e) {
  __shared__ float sc[192];
  int b = blockIdx.x;
  int i = threadIdx.x;
  if (i < 192) {
    int idx = b * 192 + i;
    float s = b2[i % 3] + part[idx] + part[196608 + idx] +
              part[2 * 196608 + idx] + part[3 * 196608 + idx];
    outS[idx] = s;
    sc[i] = s;
  }
  __syncthreads();
  if (i < 2) {
    int s = 0, e = 0;
#pragma unroll
    for (int c = 0; c < 32; ++c) {
      s |= (sc[i * 96 + c * 3 + 0] >= 0.f);
      e |= (sc[i * 96 + c * 3 + 1] >= 0.f);
    }
    is_s[2 * b + i] = s;
    is_e[2 * b + i] = e;
  }
}

// ---------- fused span: 16 spans/wave, barrier-free, 2-step unrolled ----------
__global__ __launch_bounds__(256) void spanfuse_k(
    const unsigned short* __restrict__ UVb, const unsigned short* __restrict__ bsp1b,
    const unsigned short* __restrict__ MmTb, const float* __restrict__ cvv,
    const int* __restrict__ is_s, const int* __restrict__ is_e,
    float* __restrict__ outIdx, float* __restrict__ outMask,
    float* __restrict__ outLog) {
  __shared__ __align__(16) unsigned short Rs[4][2][16][32];  // 8 KB
  int tid = threadIdx.x, lane = tid & 63, w = tid >> 6;
  int fr = lane & 15, hi = lane >> 4;
  int row = lane >> 2, q = lane & 3;
  int n = blockIdx.x * 64 + w * 16 + row;
  int wi = n / MAXW;
  int j = n - wi * MAXW;
  int er = wi + j;
  int valid = er < W_WORDS;
  int e = valid ? er : (W_WORDS - 1);
  int mask = (valid && is_s[wi] && is_e[e]) ? 1 : 0;
  if (q == 0) {
    outIdx[2 * n] = (float)wi;
    outIdx[2 * n + 1] = (float)e;
    outMask[n] = (float)mask;
  }
  int si = mask ? wi : 0, ei = mask ? e : 0;
  const unsigned short* Up = UVb + (size_t)si * 2048 + q * 8;
  const unsigned short* Vp = UVb + (size_t)ei * 2048 + 1024 + q * 8;
  const unsigned short* bp = bsp1b + q * 8;
  const unsigned short* M0 = MmTb + (size_t)fr * 1024 + hi * 8;
  const unsigned short* M1 = MmTb + (size_t)(16 + fr) * 1024 + hi * 8;
  unsigned short* wRs0 = &Rs[w][0][0][0];
  unsigned short* wRs1 = &Rs[w][1][0][0];
  int wslot = (q ^ (row & 3)) * 8;
  int rslot = ((hi ^ (fr & 3)) & 3) * 8;
  f32x4 zero4 = {0.f, 0.f, 0.f, 0.f};
  f32x4 a0 = zero4, a1 = zero4;

  bf16x8 u0 = *(const bf16x8*)Up,        v0 = *(const bf16x8*)Vp;
  bf16x8 b0 = *(const bf16x8*)bp;
  bf16x8 u1 = *(const bf16x8*)(Up + 32), v1 = *(const bf16x8*)(Vp + 32);
  bf16x8 b1v = *(const bf16x8*)(bp + 32);
  bf16x8 f00 = *(const bf16x8*)M0,        f10 = *(const bf16x8*)M1;
  bf16x8 f01 = *(const bf16x8*)(M0 + 32), f11 = *(const bf16x8*)(M1 + 32);

  for (int kt = 0; kt < 32; kt += 2) {
    int ka = ((kt + 2) & 31) * 32, kb = ((kt + 3) & 31) * 32;
    bf16x8 nu0 = *(const bf16x8*)(Up + ka), nv0 = *(const bf16x8*)(Vp + ka);
    bf16x8 nb0 = *(const bf16x8*)(bp + ka);
    bf16x8 nu1 = *(const bf16x8*)(Up + kb), nv1 = *(const bf16x8*)(Vp + kb);
    bf16x8 nb1 = *(const bf16x8*)(bp + kb);
    bf16x8 nf00 = *(const bf16x8*)(M0 + ka), nf10 = *(const bf16x8*)(M1 + ka);
    bf16x8 nf01 = *(const bf16x8*)(M0 + kb), nf11 = *(const bf16x8*)(M1 + kb);

    bf16x8 o0, o1;
#pragma unroll
    for (int i = 0; i < 8; ++i) {
      o0[i] = (short)f2b(fmaxf(b2f((unsigned short)u0[i]) + b2f((unsigned short)v0[i]) +
                               b2f((unsigned short)b0[i]), 0.f));
      o1[i] = (short)f2b(fmaxf(b2f((unsigned short)u1[i]) + b2f((unsigned short)v1[i]) +
                               b2f((unsigned short)b1v[i]), 0.f));
    }
    *(bf16x8*)&wRs0[row * 32 + wslot] = o0;
    *(bf16x8*)&wRs1[row * 32 + wslot] = o1;
    asm volatile("s_waitcnt lgkmcnt(0)" ::: "memory");
    bf16x8 fa0 = *(const bf16x8*)&wRs0[fr * 32 + rslot];
    bf16x8 fa1 = *(const bf16x8*)&wRs1[fr * 32 + rslot];
    a0 = __builtin_amdgcn_mfma_f32_16x16x32_bf16(fa0, f00, a0, 0, 0, 0);
    a1 = __builtin_amdgcn_mfma_f32_16x16x32_bf16(fa0, f10, a1, 0, 0, 0);
    a0 = __builtin_amdgcn_mfma_f32_16x16x32_bf16(fa1, f01, a0, 0, 0, 0);
    a1 = __builtin_amdgcn_mfma_f32_16x16x32_bf16(fa1, f11, a1, 0, 0, 0);
    u0 = nu0; v0 = nv0; b0 = nb0;
    u1 = nu1; v1 = nv1; b1v = nb1;
    f00 = nf00; f10 = nf10; f01 = nf01; f11 = nf11;
  }

  int n0 = blockIdx.x * 64 + w * 16;
  float c0 = cvv[fr], c1 = cvv[16 + fr];
#pragma unroll
  for (int jj = 0; jj < 4; ++jj) {
    int nn = n0 + hi * 4 + jj;
    outLog[(size_t)nn * 32 + fr] = a0[jj] + c0;
    outLog[(size_t)nn * 32 + 16 + fr] = a1[jj] + c1;
  }
}

extern "C" void kernel_launch(void* const* d_in, const int* in_sizes, int n_in,
                              void* d_out, int out_size, void* d_ws, size_t ws_size,
                              hipStream_t stream) {
  const float* hs   = (const float*)d_in[0];
  const int*   wm   = (const int*)d_in[1];
  const float* L    = (const float*)d_in[2];
  const float* Wt   = (const float*)d_in[3];
  const float* bt   = (const float*)d_in[4];
  const float* Wl   = (const float*)d_in[5];
  const float* bl   = (const float*)d_in[6];
  const float* W1a  = (const float*)d_in[7];
  const float* W1b  = (const float*)d_in[8];
  const float* W1c  = (const float*)d_in[9];
  const float* b1   = (const float*)d_in[10];
  const float* W2   = (const float*)d_in[11];
  const float* b2   = (const float*)d_in[12];
  const float* Wsp1 = (const float*)d_in[13];
  const float* bsp1 = (const float*)d_in[14];
  const float* Wsp2 = (const float*)d_in[15];
  const float* bsp2 = (const float*)d_in[16];

  char* p = (char*)d_ws;
  auto alloc = [&p](size_t bytes) {
    char* r = p;
    p += (bytes + 255) & ~(size_t)255;
    return r;
  };
  unsigned char*  we8    = (unsigned char*)alloc((size_t)2048 * 1024);
  // WtT8, Wsp1Tc8, WfuseT8 MUST be adjacent: merged BT (3584 x 1024 fp8)
  unsigned char*  WtT8    = (unsigned char*)alloc((size_t)1024 * 1024);
  unsigned char*  Wsp1Tc8 = (unsigned char*)alloc((size_t)2048 * 1024);
  unsigned char*  WfuseT8 = (unsigned char*)alloc((size_t)512 * 1024);
  unsigned char*  t1f8   = (unsigned char*)alloc((size_t)2048 * 1024);
  float*          lab    = (float*)alloc((size_t)32 * 2048 * 4);
  unsigned short* W1aT   = (unsigned short*)alloc((size_t)512 * 1024 * 2);
  unsigned short* Wtb0   = (unsigned short*)alloc((size_t)1024 * 1024 * 2);
  float*          Avec   = (float*)alloc((size_t)2048 * 512 * 4);
  float*          BvecB  = (float*)alloc((size_t)32 * 512 * 4);
  float*          bt0A   = (float*)alloc(512 * 4);
  float*          W1cT   = (float*)alloc((size_t)512 * 1024 * 4);
  unsigned char*  KT8    = (unsigned char*)alloc((size_t)16384 * 1024);
  float*          sPart  = (float*)alloc((size_t)4 * 2048 * 96 * 4);
  int*            is_s   = (int*)alloc(2048 * 4);
  int*            is_e   = (int*)alloc(2048 * 4);
  unsigned short* UVb    = (unsigned short*)alloc((size_t)2048 * 2048 * 2);
  float*          Wsp2T  = (float*)alloc((size_t)1024 * 1024 * 4);
  float*          MmTf   = (float*)alloc((size_t)32 * 1024 * 4);
  unsigned short* MmTb   = (unsigned short*)alloc((size_t)32 * 1024 * 2);
  float*          cv     = (float*)alloc(32 * 4);
  unsigned short* W2padT = (unsigned short*)alloc((size_t)16 * 512 * 2);
  unsigned short* bsp1b  = (unsigned short*)alloc((size_t)1024 * 2);

  float* outS    = (float*)d_out;
  float* outIdx  = outS + (size_t)2048 * 32 * 3;
  float* outMask = outIdx + (size_t)NSPAN * 2;
  float* outLog  = outMask + NSPAN;

  // transposes (fp8 weights) + gather (fp8 we) + Wtb0 in one launch
  mega0_k<<<dim3(96, 32, 8), dim3(32, 8), 0, stream>>>(
      hs, wm, we8, Wt, W1a, Wsp1, W1c, Wsp2, WtT8, W1aT, Wsp1Tc8, W1cT, Wsp2T, Wtb0);

  // lab = L@Wl+bl and MmTf = L@Wsp2T
  rgemm8z_k<<<dim3(128, 4, 2), 256, 0, stream>>>(L, Wl, bl, lab, Wsp2T, MmTf);

  // kmat(reg-resident) + BvecB + misc + bt0A + wfuse tiles in one launch
  mega1_k<<<545, 256, 0, stream>>>(lab, W1cT, KT8, W1b, b1, BvecB,
                                   bsp2, L, cv, MmTf, MmTb, W2, W2padT, bsp1, bsp1b,
                                   bt, W1a, bt0A, W1aT, Wtb0, WfuseT8);

  // merged fp8: [t1 | UV | Avec] = we @ [Wt_hi | Wsp1 | Wfuse]  (N = 3584)
  fgemm_k<<<dim3(28, 16), 256, 0, stream>>>(we8, WtT8, Avec, t1f8, UVb, bt, bt0A);

  // E-GEMM (MX-fp8 K=128, r14 supertile) + fused score partials
  egemm_k<<<2048, 256, 0, stream>>>(t1f8, KT8, Avec, BvecB, W2padT, sPart);

  // fold scores + masks
  foldmask_k<<<1024, 256, 0, stream>>>(sPart, b2, outS, is_s, is_e);

  // fused span: 16 spans/wave, barrier-free, 2-step unrolled
  spanfuse_k<<<384, 256, 0, stream>>>(UVb, bsp1b, MmTb, cv, is_s, is_e,
                                      outIdx, outMask, outLog);
}